// Round 1
// 4228.763 us; speedup vs baseline: 7.9228x; 7.9228x over previous
//
#include <hip/hip_runtime.h>
#include <hip/hip_bf16.h>

typedef __attribute__((ext_vector_type(8))) short short8;   // 8 x bf16 (4 VGPRs)
typedef __attribute__((ext_vector_type(4))) float floatx4;  // MFMA C/D
typedef __attribute__((ext_vector_type(4))) unsigned int uint4v;
typedef __attribute__((ext_vector_type(2))) _Float16 f16x2;

#define B_ 128
#define T_ 1024
#define H_ 256
#define G_ 1024   // 4*H

#if defined(__has_builtin)
#  if __has_builtin(__builtin_amdgcn_fdot2)
#    define HAS_FDOT2 1
#  endif
#endif

__device__ __forceinline__ float sigmoidf_(float x) {
    x = fminf(fmaxf(x, -30.f), 30.f);
    return 1.0f / (1.0f + __expf(-x));
}
__device__ __forceinline__ float tanhf_(float x) {
    x = fminf(fmaxf(x, -15.f), 15.f);
    float e = __expf(2.0f * x);
    return 1.0f - 2.0f / (e + 1.0f);
}
__device__ __forceinline__ unsigned short f2bu(float x) {
    __hip_bfloat16 b = __float2bfloat16(x);
    return *reinterpret_cast<unsigned short*>(&b);
}

// packed-f16 dot2 with f32 accumulate (v_dot2_f32_f16 when available)
__device__ __forceinline__ float dot2_(unsigned int w, unsigned int h, float acc) {
    f16x2 wv = __builtin_bit_cast(f16x2, w);
    f16x2 hv = __builtin_bit_cast(f16x2, h);
#ifdef HAS_FDOT2
    return __builtin_amdgcn_fdot2(wv, hv, acc, false);
#else
    return fmaf((float)wv.x, (float)hv.x, fmaf((float)wv.y, (float)hv.y, acc));
#endif
}

// ---------------------------------------------------------------------------
// GEMM, f32 in / f32 out, bf16 MFMA internally.  (unchanged, m92-lineage)
// C[rm,n] = sum_k A[rm,k]*Wt[n,k] + b1[n] (+ b2[n])
// ---------------------------------------------------------------------------
__global__ __launch_bounds__(256) void gemm_bias_f32(
    const float* __restrict__ A,
    const float* __restrict__ Wt,        // [N][K] row-major
    const float* __restrict__ bias1,
    const float* __restrict__ bias2,     // nullable
    float* __restrict__ C,
    int d2shift, long sa1, long sa2, long sc1, long sc2, int K)
{
    __shared__ __hip_bfloat16 a_tile[64][40];  // 32 K + 8 pad
    __shared__ __hip_bfloat16 b_tile[64][40];

    const int tid  = threadIdx.x;
    const int wave = tid >> 6;
    const int lane = tid & 63;
    const int quad = lane >> 4;
    const int l16  = lane & 15;

    const int bm = blockIdx.x * 64;
    const int bn = blockIdx.y * 64;
    const int mask = (1 << d2shift) - 1;

    const int lr  = tid >> 2;   // staging row 0..63
    const int seg = tid & 3;    // 8-element segment

    const int grow = bm + lr;
    const float* abase =
        A + (long)(grow >> d2shift) * sa1 + (long)(grow & mask) * sa2 + seg * 8;
    const float* bbase = Wt + (long)(bn + lr) * K + seg * 8;

    floatx4 acc[4];
    #pragma unroll
    for (int nt = 0; nt < 4; ++nt) acc[nt] = (floatx4){0.f, 0.f, 0.f, 0.f};

    for (int kk = 0; kk < K; kk += 32) {
        float4 a0 = *(const float4*)(abase + kk);
        float4 a1 = *(const float4*)(abase + kk + 4);
        float4 b0 = *(const float4*)(bbase + kk);
        float4 b1 = *(const float4*)(bbase + kk + 4);
        uint4 ap, bp;
        ap.x = f2bu(a0.x) | ((unsigned)f2bu(a0.y) << 16);
        ap.y = f2bu(a0.z) | ((unsigned)f2bu(a0.w) << 16);
        ap.z = f2bu(a1.x) | ((unsigned)f2bu(a1.y) << 16);
        ap.w = f2bu(a1.z) | ((unsigned)f2bu(a1.w) << 16);
        bp.x = f2bu(b0.x) | ((unsigned)f2bu(b0.y) << 16);
        bp.y = f2bu(b0.z) | ((unsigned)f2bu(b0.w) << 16);
        bp.z = f2bu(b1.x) | ((unsigned)f2bu(b1.y) << 16);
        bp.w = f2bu(b1.z) | ((unsigned)f2bu(b1.w) << 16);
        __syncthreads();  // prior iter's LDS reads done
        *(uint4*)&a_tile[lr][seg * 8] = ap;
        *(uint4*)&b_tile[lr][seg * 8] = bp;
        __syncthreads();
        short8 af = *(const short8*)&a_tile[wave * 16 + l16][quad * 8];
        #pragma unroll
        for (int nt = 0; nt < 4; ++nt) {
            short8 bf = *(const short8*)&b_tile[nt * 16 + l16][quad * 8];
            acc[nt] = __builtin_amdgcn_mfma_f32_16x16x32_bf16(af, bf, acc[nt], 0, 0, 0);
        }
    }

    // epilogue: C/D layout col = lane&15, row = quad*4 + r
    #pragma unroll
    for (int nt = 0; nt < 4; ++nt) {
        const int col = bn + nt * 16 + l16;
        float bsum = bias1[col];
        if (bias2) bsum += bias2[col];
        #pragma unroll
        for (int r = 0; r < 4; ++r) {
            const int rm = bm + wave * 16 + quad * 4 + r;
            const long off = (long)(rm >> d2shift) * sc1 + (long)(rm & mask) * sc2;
            C[off + col] = acc[nt][r] + bsum;
        }
    }
}

// ---------------------------------------------------------------------------
// Pack w_hh [1024][256] f32 into the recurrence-kernel weight layouts (f16):
//  wrg: [2 kh][3 gate(i,f,g)][64 kp][256 j] half2   (register-resident gates)
//  wo : [256 j][128 kp] half2                       (LDS-resident o gate)
//  half2 at kp pairs k = {kh*128 + 2kp, kh*128 + 2kp + 1} (wo: k = {2kp,2kp+1})
// ---------------------------------------------------------------------------
__global__ __launch_bounds__(256) void pack_whh(
    const float* __restrict__ w,        // [1024][256]
    unsigned int* __restrict__ wrg,     // 98304 dwords
    unsigned int* __restrict__ wo)      // 32768 dwords
{
    const int idx = blockIdx.x * 256 + threadIdx.x;   // 0..131071
    if (idx < 98304) {
        const int kh = idx / 49152;          // 49152 = 3*64*256
        const int r  = idx % 49152;
        const int g  = r >> 14;              // /16384
        const int r2 = r & 16383;
        const int kp = r2 >> 8;
        const int jj = r2 & 255;
        const long src = (long)(g * 256 + jj) * 256 + kh * 128 + kp * 2;
        f16x2 pk;
        pk.x = (_Float16)w[src];
        pk.y = (_Float16)w[src + 1];
        wrg[idx] = __builtin_bit_cast(unsigned int, pk);
    } else {
        const int i2 = idx - 98304;
        const int jj = i2 >> 7;
        const int kp = i2 & 127;
        const long src = (long)(768 + jj) * 256 + kp * 2;
        f16x2 pk;
        pk.x = (_Float16)w[src];
        pk.y = (_Float16)w[src + 1];
        wo[i2] = __builtin_bit_cast(unsigned int, pk);
    }
}

// ---------------------------------------------------------------------------
// Register/LDS-resident LSTM recurrence. One block per batch row (128 blocks).
// 512 threads = (unit j = tid&255) x (k-half kh = tid>>8).
// Thread holds i,f,g gate weights for its (j, k-half) in 192 VGPRs (half2);
// o-gate weights live in 128 KB LDS (XOR-swizzled 16B granules).
// h feedback is published per step as f16 in LDS (broadcast reads).
// k-half partial sums combine through a small LDS buffer; kh==0 finishes.
// ---------------------------------------------------------------------------
__global__ __launch_bounds__(512, 2) void lstm_reg(
    const float* __restrict__ xg,           // [Tc][B][G] (incl. both biases)
    const unsigned int* __restrict__ wrg,   // [2][3][64][256] half2
    const unsigned int* __restrict__ wo,    // [256][128] half2
    float* __restrict__ h_seq,              // [Tc][B][H]
    const float* __restrict__ h_in,         // [B][H]
    const float* __restrict__ c_in,         // [B][H]
    float* __restrict__ h_out,              // [B][H]
    float* __restrict__ c_out,              // [B][H]
    float* __restrict__ c_fin,              // nullable [B][H]
    int Tc, int init)
{
    const int tid = threadIdx.x;
    const int j   = tid & 255;
    const int kh  = tid >> 8;
    const int b   = blockIdx.x;

    __shared__ __align__(16) unsigned int wo_lds[32768];  // 128 KB
    __shared__ __align__(16) float part[256][4];          // 4 KB
    __shared__ __align__(16) _Float16 hpk[256];           // 512 B

    // ---- load register weights (i,f,g gates; this thread's k-half) ----
    unsigned int wi_[64], wf_[64], wg_[64];
    {
        const unsigned int* wb = wrg + (long)kh * 49152 + j;
        #pragma unroll
        for (int kp = 0; kp < 64; ++kp) wi_[kp] = wb[kp * 256];
        #pragma unroll
        for (int kp = 0; kp < 64; ++kp) wf_[kp] = wb[16384 + kp * 256];
        #pragma unroll
        for (int kp = 0; kp < 64; ++kp) wg_[kp] = wb[32768 + kp * 256];
    }

    // ---- stage o-gate weights into LDS, swizzled: granule ^= (row & 31) ----
    for (int it = 0; it < 64; ++it) {
        const int d    = it * 512 + tid;    // 0..32767, coalesced
        const int jr   = d >> 7;
        const int kp   = d & 127;
        const int slot = (kp >> 2) ^ (jr & 31);
        wo_lds[jr * 128 + slot * 4 + (kp & 3)] = wo[d];
    }

    // ---- init state ----
    float c = 0.f, hlast = 0.f;
    if (kh == 0) {
        float h0 = 0.f;
        if (!init) {
            h0 = h_in[(long)b * H_ + j];
            c  = c_in[(long)b * H_ + j];
        }
        hlast = h0;
        hpk[j] = (_Float16)h0;
    }
    __syncthreads();   // wo_lds staging + hpk init visible

    // xg prefetch for t=0 (kh==0 only; kh==1 partials start at 0)
    const float* xbase = xg + (long)b * G_ + j;
    float nI = 0.f, nF = 0.f, nG = 0.f, nO = 0.f;
    if (kh == 0) {
        nI = xbase[0]; nF = xbase[256]; nG = xbase[512]; nO = xbase[768];
    }

    const int jx = j & 31;

    for (int t = 0; t < Tc; ++t) {
        __syncthreads();  // hpk(t) writes visible; prior part reads done

        float aI = nI, aF = nF, aG = nG, aO = nO;
        if (kh == 0 && t + 1 < Tc) {       // prefetch next step's xg
            const float* xn = xbase + (long)(t + 1) * (B_ * G_);
            nI = xn[0]; nF = xn[256]; nG = xn[512]; nO = xn[768];
        }

        // 128 k values (64 half2) for this k-half, all 4 gates
        #pragma unroll
        for (int q = 0; q < 16; ++q) {
            const int gi = kh * 16 + q;                               // granule
            uint4v hv = *(const uint4v*)&hpk[gi * 8];                 // broadcast
            uint4v wv = *(const uint4v*)&wo_lds[j * 128 + ((gi ^ jx) << 2)];
            #pragma unroll
            for (int e = 0; e < 4; ++e) {
                const int kp = q * 4 + e;
                aI = dot2_(wi_[kp], hv[e], aI);
                aF = dot2_(wf_[kp], hv[e], aF);
                aG = dot2_(wg_[kp], hv[e], aG);
                aO = dot2_(wv[e],   hv[e], aO);
            }
        }

        if (kh) {
            float4 pp; pp.x = aI; pp.y = aF; pp.z = aG; pp.w = aO;
            *(float4*)&part[j][0] = pp;
        }
        __syncthreads();  // partials visible; all hpk(t) reads done
        if (!kh) {
            float4 pp = *(const float4*)&part[j][0];
            const float iv = sigmoidf_(aI + pp.x);
            const float fv = sigmoidf_(aF + pp.y);
            const float gv = tanhf_(aG + pp.z);
            const float ov = sigmoidf_(aO + pp.w);
            c = fv * c + iv * gv;
            const float hv2 = ov * tanhf_(c);
            hlast = hv2;
            h_seq[((long)t * B_ + b) * H_ + j] = hv2;
            hpk[j] = (_Float16)hv2;          // feedback for t+1
        }
    }

    if (kh == 0) {
        h_out[(long)b * H_ + j] = hlast;
        c_out[(long)b * H_ + j] = c;
        if (c_fin) c_fin[(long)b * H_ + j] = c;
    }
}

// ---------------------------------------------------------------------------
extern "C" void kernel_launch(void* const* d_in, const int* in_sizes, int n_in,
                              void* d_out, int out_size, void* d_ws, size_t ws_size,
                              hipStream_t stream)
{
    const float* x     = (const float*)d_in[0];   // [B][T][128]
    const float* w_ih0 = (const float*)d_in[1];   // [1024][128]
    const float* w_hh0 = (const float*)d_in[2];   // [1024][256]
    const float* b_ih0 = (const float*)d_in[3];
    const float* b_hh0 = (const float*)d_in[4];
    const float* w_ih1 = (const float*)d_in[5];   // [1024][256]
    const float* w_hh1 = (const float*)d_in[6];   // [1024][256]
    const float* b_ih1 = (const float*)d_in[7];
    const float* b_hh1 = (const float*)d_in[8];
    const float* w_lin = (const float*)d_in[9];   // [128][256]
    const float* b_lin = (const float*)d_in[10];

    float* out  = (float*)d_out;                   // [B][T][128]
    float* hfin = out + (size_t)B_ * T_ * 128;     // [2][B][H]
    float* cfin = hfin + 2 * (B_ * H_);            // [2][B][H]

    // ---- fixed workspace: packed f16 weights + state carry ≈ 1.5 MB ----
    char* p = (char*)d_ws;
    unsigned int* wp0 = (unsigned int*)p;  p += 131072 * 4;   // 512 KB
    unsigned int* wp1 = (unsigned int*)p;  p += 131072 * 4;   // 512 KB
    float* h0st = (float*)p;  p += 131072;                    // [B][H] f32
    float* h1st = (float*)p;  p += 131072;
    float* c0st = (float*)p;  p += 131072;
    float* c1st = (float*)p;  p += 131072;
    const size_t fixed = (size_t)(p - (char*)d_ws);

    // per chunk: xg Tc*524288 B + h0c/h1c Tc*131072 B each = Tc*786432 B
    int Tc = 1024;
    while (Tc > 1 && fixed + (size_t)Tc * 786432u > ws_size) Tc >>= 1;
    const int nc = T_ / Tc;
    const int tshift = __builtin_ctz((unsigned)Tc);

    float* xgc = (float*)p;  p += (size_t)Tc * 524288;    // [Tc][B][G]
    float* h0c = (float*)p;  p += (size_t)Tc * 131072;    // [Tc][B][H]
    float* h1c = (float*)p;                               // [Tc][B][H]

    // ---- pack both recurrence weight matrices once (f32 -> f16 layouts) ----
    pack_whh<<<dim3(512), dim3(256), 0, stream>>>(w_hh0, wp0, wp0 + 98304);
    pack_whh<<<dim3(512), dim3(256), 0, stream>>>(w_hh1, wp1, wp1 + 98304);

    // ---- chunked pipeline ----
    for (int i = 0; i < nc; ++i) {
        const long t0   = (long)i * Tc;
        const int  init = (i == 0);
        const int  last = (i == nc - 1);

        // xg0[tl*B+b, g] = x[b, t0+tl, :] . w_ih0[g,:] + b_ih0 + b_hh0
        gemm_bias_f32<<<dim3(2 * Tc, 16), dim3(256), 0, stream>>>(
            x + t0 * 128, w_ih0, b_ih0, b_hh0, xgc,
            7, 128L, 131072L, 131072L, 1024L, 128);

        lstm_reg<<<dim3(B_), dim3(512), 0, stream>>>(
            xgc, wp0, wp0 + 98304, h0c, h0st, c0st,
            last ? hfin : h0st, c0st, last ? cfin : (float*)nullptr,
            Tc, init);

        // xg1[tl*B+b, g] = h0c[tl, b, :] . w_ih1[g,:] + b_ih1 + b_hh1
        gemm_bias_f32<<<dim3(2 * Tc, 16), dim3(256), 0, stream>>>(
            h0c, w_ih1, b_ih1, b_hh1, xgc,
            7, 32768L, 256L, 131072L, 1024L, 256);

        lstm_reg<<<dim3(B_), dim3(512), 0, stream>>>(
            xgc, wp1, wp1 + 98304, h1c, h1st, c1st,
            last ? hfin + B_ * H_ : h1st, c1st,
            last ? cfin + B_ * H_ : (float*)nullptr,
            Tc, init);

        // out[b, t0+tl, o] = h1c[tl, b, :] . w_lin[o,:] + b_lin ; rm = b*Tc + tl
        gemm_bias_f32<<<dim3(2 * Tc, 2), dim3(256), 0, stream>>>(
            h1c, w_lin, b_lin, (const float*)nullptr, out + t0 * 128,
            tshift, 256L, 32768L, 131072L, 128L, 256);
    }
}

// Round 2
// 2399.744 us; speedup vs baseline: 13.9613x; 1.7622x over previous
//
#include <hip/hip_runtime.h>
#include <hip/hip_bf16.h>

typedef __attribute__((ext_vector_type(8))) short short8;   // 8 x bf16 (4 VGPRs)
typedef __attribute__((ext_vector_type(4))) float floatx4;  // MFMA C/D
typedef __attribute__((ext_vector_type(4))) unsigned int uint4v;
typedef __attribute__((ext_vector_type(2))) _Float16 f16x2;

#define B_ 128
#define T_ 1024
#define H_ 256
#define G_ 1024   // 4*H

#if defined(__has_builtin)
#  if __has_builtin(__builtin_amdgcn_fdot2)
#    define HAS_FDOT2 1
#  endif
#endif

__device__ __forceinline__ float sigmoidf_(float x) {
    x = fminf(fmaxf(x, -30.f), 30.f);
    return 1.0f / (1.0f + __expf(-x));
}
__device__ __forceinline__ float tanhf_(float x) {
    x = fminf(fmaxf(x, -15.f), 15.f);
    float e = __expf(2.0f * x);
    return 1.0f - 2.0f / (e + 1.0f);
}
__device__ __forceinline__ unsigned short f2bu(float x) {
    __hip_bfloat16 b = __float2bfloat16(x);
    return *reinterpret_cast<unsigned short*>(&b);
}

// packed-f16 dot2 with f32 accumulate — exactly one VALU op per half2 pair.
// builtin if the compiler has it; otherwise raw v_dot2_f32_f16 (CDNA VOP3P).
__device__ __forceinline__ float dot2_(unsigned int w, unsigned int h, float acc) {
#ifdef HAS_FDOT2
    return __builtin_amdgcn_fdot2(__builtin_bit_cast(f16x2, w),
                                  __builtin_bit_cast(f16x2, h), acc, false);
#else
    float d;
    asm("v_dot2_f32_f16 %0, %1, %2, %3" : "=v"(d) : "v"(w), "v"(h), "v"(acc));
    return d;
#endif
}

// ---------------------------------------------------------------------------
// GEMM, f32 in / f32 out, bf16 MFMA internally.  (unchanged, m92-lineage)
// C[rm,n] = sum_k A[rm,k]*Wt[n,k] + b1[n] (+ b2[n])
// ---------------------------------------------------------------------------
__global__ __launch_bounds__(256) void gemm_bias_f32(
    const float* __restrict__ A,
    const float* __restrict__ Wt,        // [N][K] row-major
    const float* __restrict__ bias1,
    const float* __restrict__ bias2,     // nullable
    float* __restrict__ C,
    int d2shift, long sa1, long sa2, long sc1, long sc2, int K)
{
    __shared__ __hip_bfloat16 a_tile[64][40];  // 32 K + 8 pad
    __shared__ __hip_bfloat16 b_tile[64][40];

    const int tid  = threadIdx.x;
    const int wave = tid >> 6;
    const int lane = tid & 63;
    const int quad = lane >> 4;
    const int l16  = lane & 15;

    const int bm = blockIdx.x * 64;
    const int bn = blockIdx.y * 64;
    const int mask = (1 << d2shift) - 1;

    const int lr  = tid >> 2;   // staging row 0..63
    const int seg = tid & 3;    // 8-element segment

    const int grow = bm + lr;
    const float* abase =
        A + (long)(grow >> d2shift) * sa1 + (long)(grow & mask) * sa2 + seg * 8;
    const float* bbase = Wt + (long)(bn + lr) * K + seg * 8;

    floatx4 acc[4];
    #pragma unroll
    for (int nt = 0; nt < 4; ++nt) acc[nt] = (floatx4){0.f, 0.f, 0.f, 0.f};

    for (int kk = 0; kk < K; kk += 32) {
        float4 a0 = *(const float4*)(abase + kk);
        float4 a1 = *(const float4*)(abase + kk + 4);
        float4 b0 = *(const float4*)(bbase + kk);
        float4 b1 = *(const float4*)(bbase + kk + 4);
        uint4 ap, bp;
        ap.x = f2bu(a0.x) | ((unsigned)f2bu(a0.y) << 16);
        ap.y = f2bu(a0.z) | ((unsigned)f2bu(a0.w) << 16);
        ap.z = f2bu(a1.x) | ((unsigned)f2bu(a1.y) << 16);
        ap.w = f2bu(a1.z) | ((unsigned)f2bu(a1.w) << 16);
        bp.x = f2bu(b0.x) | ((unsigned)f2bu(b0.y) << 16);
        bp.y = f2bu(b0.z) | ((unsigned)f2bu(b0.w) << 16);
        bp.z = f2bu(b1.x) | ((unsigned)f2bu(b1.y) << 16);
        bp.w = f2bu(b1.z) | ((unsigned)f2bu(b1.w) << 16);
        __syncthreads();  // prior iter's LDS reads done
        *(uint4*)&a_tile[lr][seg * 8] = ap;
        *(uint4*)&b_tile[lr][seg * 8] = bp;
        __syncthreads();
        short8 af = *(const short8*)&a_tile[wave * 16 + l16][quad * 8];
        #pragma unroll
        for (int nt = 0; nt < 4; ++nt) {
            short8 bf = *(const short8*)&b_tile[nt * 16 + l16][quad * 8];
            acc[nt] = __builtin_amdgcn_mfma_f32_16x16x32_bf16(af, bf, acc[nt], 0, 0, 0);
        }
    }

    // epilogue: C/D layout col = lane&15, row = quad*4 + r
    #pragma unroll
    for (int nt = 0; nt < 4; ++nt) {
        const int col = bn + nt * 16 + l16;
        float bsum = bias1[col];
        if (bias2) bsum += bias2[col];
        #pragma unroll
        for (int r = 0; r < 4; ++r) {
            const int rm = bm + wave * 16 + quad * 4 + r;
            const long off = (long)(rm >> d2shift) * sc1 + (long)(rm & mask) * sc2;
            C[off + col] = acc[nt][r] + bsum;
        }
    }
}

// ---------------------------------------------------------------------------
// Pack w_hh [1024][256] f32 into the recurrence-kernel weight layouts (f16):
//  wrg: [2 kh][3 gate(i,f,g)][64 kp][256 j] half2   (register-resident gates)
//  wo : [256 j][128 kp] half2                       (LDS-resident o gate)
// ---------------------------------------------------------------------------
__global__ __launch_bounds__(256) void pack_whh(
    const float* __restrict__ w,        // [1024][256]
    unsigned int* __restrict__ wrg,     // 98304 dwords
    unsigned int* __restrict__ wo)      // 32768 dwords
{
    const int idx = blockIdx.x * 256 + threadIdx.x;   // 0..131071
    if (idx < 98304) {
        const int kh = idx / 49152;          // 49152 = 3*64*256
        const int r  = idx % 49152;
        const int g  = r >> 14;              // /16384
        const int r2 = r & 16383;
        const int kp = r2 >> 8;
        const int jj = r2 & 255;
        const long src = (long)(g * 256 + jj) * 256 + kh * 128 + kp * 2;
        f16x2 pk;
        pk.x = (_Float16)w[src];
        pk.y = (_Float16)w[src + 1];
        wrg[idx] = __builtin_bit_cast(unsigned int, pk);
    } else {
        const int i2 = idx - 98304;
        const int jj = i2 >> 7;
        const int kp = i2 & 127;
        const long src = (long)(768 + jj) * 256 + kp * 2;
        f16x2 pk;
        pk.x = (_Float16)w[src];
        pk.y = (_Float16)w[src + 1];
        wo[i2] = __builtin_bit_cast(unsigned int, pk);
    }
}

// ---------------------------------------------------------------------------
// Per-layer recurrence arguments (fused dispatch carries two of these).
// ---------------------------------------------------------------------------
struct LArgs {
    const float* xg;            // [Tc][B][G] (incl. both biases)
    const unsigned int* wrg;    // [2][3][64][256] half2
    const unsigned int* wo;     // [256][128] half2
    float* h_seq;               // [Tc][B][H]
    const float* h_in;          // [B][H]
    const float* c_in;          // [B][H]
    float* h_out;               // [B][H]
    float* c_out;               // [B][H]
    float* c_fin;               // nullable [B][H]
    int Tc;
    int init;
    int valid;
};

// ---------------------------------------------------------------------------
// Register/LDS-resident LSTM recurrence body. One block per batch row.
// 512 threads = (unit j = tid&255) x (k-half kh = tid>>8).
// i,f,g gate weights in registers (192 half2-dwords/thread); o gate in
// 128 KB XOR-swizzled LDS; h feedback published per step as f16 in LDS.
// ---------------------------------------------------------------------------
__device__ __forceinline__ void lstm_body(const LArgs& A, int b)
{
    const int tid = threadIdx.x;
    const int j   = tid & 255;
    const int kh  = tid >> 8;

    __shared__ __align__(16) unsigned int wo_lds[32768];  // 128 KB
    __shared__ __align__(16) float part[256][4];          // 4 KB
    __shared__ __align__(16) _Float16 hpk[256];           // 512 B

    const int Tc = A.Tc;

    // ---- load register weights (i,f,g gates; this thread's k-half) ----
    unsigned int wi_[64], wf_[64], wg_[64];
    {
        const unsigned int* wb = A.wrg + (long)kh * 49152 + j;
        #pragma unroll
        for (int kp = 0; kp < 64; ++kp) wi_[kp] = wb[kp * 256];
        #pragma unroll
        for (int kp = 0; kp < 64; ++kp) wf_[kp] = wb[16384 + kp * 256];
        #pragma unroll
        for (int kp = 0; kp < 64; ++kp) wg_[kp] = wb[32768 + kp * 256];
    }

    // ---- stage o-gate weights into LDS, swizzled: slot ^= (row & 31) ----
    for (int it = 0; it < 64; ++it) {
        const int d    = it * 512 + tid;    // 0..32767, coalesced
        const int jr   = d >> 7;
        const int kp   = d & 127;
        const int slot = (kp >> 2) ^ (jr & 31);
        wo_lds[jr * 128 + slot * 4 + (kp & 3)] = A.wo[d];
    }

    // ---- init state ----
    float c = 0.f, hlast = 0.f;
    if (kh == 0) {
        float h0 = 0.f;
        if (!A.init) {
            h0 = A.h_in[(long)b * H_ + j];
            c  = A.c_in[(long)b * H_ + j];
        }
        hlast = h0;
        hpk[j] = (_Float16)h0;
    }
    __syncthreads();   // wo_lds staging + hpk init visible

    // xg prefetch for t=0 (kh==0 only; kh==1 partials start at 0)
    const float* xbase = A.xg + (long)b * G_ + j;
    float nI = 0.f, nF = 0.f, nG = 0.f, nO = 0.f;
    if (kh == 0) {
        nI = xbase[0]; nF = xbase[256]; nG = xbase[512]; nO = xbase[768];
    }

    const int jx = j & 31;

    for (int t = 0; t < Tc; ++t) {
        __syncthreads();  // hpk(t) writes visible; prior part reads done

        float aI = nI, aF = nF, aG = nG, aO = nO;
        if (kh == 0 && t + 1 < Tc) {       // prefetch next step's xg
            const float* xn = xbase + (long)(t + 1) * (B_ * G_);
            nI = xn[0]; nF = xn[256]; nG = xn[512]; nO = xn[768];
        }

        // 128 k values (64 half2) for this k-half, all 4 gates
        #pragma unroll
        for (int q = 0; q < 16; ++q) {
            const int gi = kh * 16 + q;                               // granule
            uint4v hv = *(const uint4v*)&hpk[gi * 8];                 // broadcast
            uint4v wv = *(const uint4v*)&wo_lds[j * 128 + ((gi ^ jx) << 2)];
            #pragma unroll
            for (int e = 0; e < 4; ++e) {
                const int kp = q * 4 + e;
                aI = dot2_(wi_[kp], hv[e], aI);
                aF = dot2_(wf_[kp], hv[e], aF);
                aG = dot2_(wg_[kp], hv[e], aG);
                aO = dot2_(wv[e],   hv[e], aO);
            }
        }

        if (kh) {
            float4 pp; pp.x = aI; pp.y = aF; pp.z = aG; pp.w = aO;
            *(float4*)&part[j][0] = pp;
        }
        __syncthreads();  // partials visible; all hpk(t) reads done
        if (!kh) {
            float4 pp = *(const float4*)&part[j][0];
            const float iv = sigmoidf_(aI + pp.x);
            const float fv = sigmoidf_(aF + pp.y);
            const float gv = tanhf_(aG + pp.z);
            const float ov = sigmoidf_(aO + pp.w);
            c = fv * c + iv * gv;
            const float hv2 = ov * tanhf_(c);
            hlast = hv2;
            A.h_seq[((long)t * B_ + b) * H_ + j] = hv2;
            hpk[j] = (_Float16)hv2;          // feedback for t+1
        }
    }

    if (kh == 0) {
        A.h_out[(long)b * H_ + j] = hlast;
        A.c_out[(long)b * H_ + j] = c;
        if (A.c_fin) A.c_fin[(long)b * H_ + j] = c;
    }
}

// Fused dispatch: blocks 0..127 run a0 (layer-1 chunk i), blocks 128..255 run
// a1 (layer-0 chunk i+1). Layers are independent -> both halves of the chip
// stay busy (software-pipelined across the chunk boundary).
__global__ __launch_bounds__(512, 2) void lstm_fused(LArgs a0, LArgs a1)
{
    const LArgs& A = (blockIdx.x < 128) ? a0 : a1;
    if (!A.valid) return;
    lstm_body(A, blockIdx.x & 127);
}

// ---------------------------------------------------------------------------
extern "C" void kernel_launch(void* const* d_in, const int* in_sizes, int n_in,
                              void* d_out, int out_size, void* d_ws, size_t ws_size,
                              hipStream_t stream)
{
    const float* x     = (const float*)d_in[0];   // [B][T][128]
    const float* w_ih0 = (const float*)d_in[1];   // [1024][128]
    const float* w_hh0 = (const float*)d_in[2];   // [1024][256]
    const float* b_ih0 = (const float*)d_in[3];
    const float* b_hh0 = (const float*)d_in[4];
    const float* w_ih1 = (const float*)d_in[5];   // [1024][256]
    const float* w_hh1 = (const float*)d_in[6];   // [1024][256]
    const float* b_ih1 = (const float*)d_in[7];
    const float* b_hh1 = (const float*)d_in[8];
    const float* w_lin = (const float*)d_in[9];   // [128][256]
    const float* b_lin = (const float*)d_in[10];

    float* out  = (float*)d_out;                   // [B][T][128]
    float* hfin = out + (size_t)B_ * T_ * 128;     // [2][B][H]
    float* cfin = hfin + 2 * (B_ * H_);            // [2][B][H]

    // ---- fixed workspace: packed f16 weights + state carry ≈ 1.5 MB ----
    char* p = (char*)d_ws;
    unsigned int* wp0 = (unsigned int*)p;  p += 131072 * 4;   // 512 KB
    unsigned int* wp1 = (unsigned int*)p;  p += 131072 * 4;   // 512 KB
    float* h0st = (float*)p;  p += 131072;                    // [B][H] f32
    float* h1st = (float*)p;  p += 131072;
    float* c0st = (float*)p;  p += 131072;
    float* c1st = (float*)p;  p += 131072;
    const size_t fixed = (size_t)(p - (char*)d_ws);

    // per chunk: xg0 + xg1 (Tc*524288 B each) + h0c + h1c (Tc*131072 B each)
    int Tc = 1024;
    while (Tc > 1 && fixed + (size_t)Tc * 1310720u > ws_size) Tc >>= 1;
    const int nc = T_ / Tc;
    const int tshift = __builtin_ctz((unsigned)Tc);

    float* xg0 = (float*)p;  p += (size_t)Tc * 524288;    // [Tc][B][G] layer0
    float* xg1 = (float*)p;  p += (size_t)Tc * 524288;    // [Tc][B][G] layer1
    float* h0c = (float*)p;  p += (size_t)Tc * 131072;    // [Tc][B][H]
    float* h1c = (float*)p;                               // [Tc][B][H]

    // ---- pack both recurrence weight matrices once (f32 -> f16 layouts) ----
    pack_whh<<<dim3(512), dim3(256), 0, stream>>>(w_hh0, wp0, wp0 + 98304);
    pack_whh<<<dim3(512), dim3(256), 0, stream>>>(w_hh1, wp1, wp1 + 98304);

    LArgs inv{};  inv.valid = 0;

    auto L0args = [&](int i) {
        LArgs a;
        a.xg = xg0; a.wrg = wp0; a.wo = wp0 + 98304;
        a.h_seq = h0c; a.h_in = h0st; a.c_in = c0st;
        a.h_out = (i == nc - 1) ? hfin : h0st;
        a.c_out = c0st;
        a.c_fin = (i == nc - 1) ? cfin : (float*)nullptr;
        a.Tc = Tc; a.init = (i == 0); a.valid = 1;
        return a;
    };
    auto L1args = [&](int i) {
        LArgs a;
        a.xg = xg1; a.wrg = wp1; a.wo = wp1 + 98304;
        a.h_seq = h1c; a.h_in = h1st; a.c_in = c1st;
        a.h_out = (i == nc - 1) ? (hfin + B_ * H_) : h1st;
        a.c_out = c1st;
        a.c_fin = (i == nc - 1) ? (cfin + B_ * H_) : (float*)nullptr;
        a.Tc = Tc; a.init = (i == 0); a.valid = 1;
        return a;
    };

    auto gemm0 = [&](int i) {   // xg0 <- x(chunk i) . w_ih0^T + b_ih0 + b_hh0
        gemm_bias_f32<<<dim3(2 * Tc, 16), dim3(256), 0, stream>>>(
            x + (long)i * Tc * 128, w_ih0, b_ih0, b_hh0, xg0,
            7, 128L, 131072L, 131072L, 1024L, 128);
    };

    // ---- software-pipelined schedule ----
    gemm0(0);
    lstm_fused<<<dim3(256), dim3(512), 0, stream>>>(inv, L0args(0));

    for (int i = 0; i < nc; ++i) {
        // xg1 <- h0c(chunk i) . w_ih1^T + b_ih1 + b_hh1
        gemm_bias_f32<<<dim3(2 * Tc, 16), dim3(256), 0, stream>>>(
            h0c, w_ih1, b_ih1, b_hh1, xg1,
            7, 32768L, 256L, 131072L, 1024L, 256);

        if (i + 1 < nc) gemm0(i + 1);

        lstm_fused<<<dim3(256), dim3(512), 0, stream>>>(
            L1args(i), (i + 1 < nc) ? L0args(i + 1) : inv);

        // out(chunk i) <- h1c . w_lin^T + b_lin ; rm = b*Tc + tl
        gemm_bias_f32<<<dim3(2 * Tc, 2), dim3(256), 0, stream>>>(
            h1c, w_lin, b_lin, (const float*)nullptr, out + (long)i * Tc * 128,
            tshift, 256L, 32768L, 131072L, 128L, 256);
    }
}